// Round 14
// baseline (688.176 us; speedup 1.0000x reference)
//
#include <hip/hip_runtime.h>
#include <hip/hip_bf16.h>

typedef __bf16 bf16_t;
typedef __bf16 bf16x8 __attribute__((ext_vector_type(8)));
typedef float  f32x4  __attribute__((ext_vector_type(4)));

#define B_ 8
#define T_ 2048
#define C_ 1024
#define H_ 64

#define MFMA16(a, b, c) __builtin_amdgcn_mfma_f32_16x16x32_bf16((a), (b), (c), 0, 0, 0)
// async global->LDS, 16B per lane; dest = wave-uniform base + lane*16 (linear)
#define GLL16(g, l) __builtin_amdgcn_global_load_lds( \
    (const __attribute__((address_space(1))) unsigned int*)(g), \
    (__attribute__((address_space(3))) unsigned int*)(l), 16, 0, 0)
// RAW barrier (__syncthreads drains all vmcnt -> defeats prefetch)
#define SBAR() asm volatile("s_barrier" ::: "memory")

// ---------------------------------------------------------------------------
// R14: fused proj->attn->div in ONE regular (graph-capturable) launch with a
// hand-rolled grid barrier.  R13's cooperative launch never executed (out
// stayed zero: absmax == max|ref|); hipLaunchCooperativeKernel is presumed
// incompatible with the harness's graph capture.  Mechanism here:
//  - monotonic counter in ws, zeroed by a 4-byte hipMemsetAsync each launch
//  - arrival: agent-scope fetch_add(release); spin: agent-scope load(acquire)
//  - __threadfence() at the boundary = agent fence -> L2 wb/inv, giving
//    cross-XCD visibility of qh/ql/kh/kl/vh and Oacc between phases
//  - deadlock-free by construction: 72KB LDS -> exactly 2 blocks/CU, grid
//    512 = 2x256 CUs -> all blocks co-resident, every arrival guaranteed.
// ---------------------------------------------------------------------------
__device__ __forceinline__ void grid_barrier(unsigned* ctr, unsigned target)
{
    __syncthreads();
    __threadfence();                       // release: prior writes agent-wide
    if (threadIdx.x == 0) {
        __hip_atomic_fetch_add(ctr, 1u, __ATOMIC_RELEASE, __HIP_MEMORY_SCOPE_AGENT);
        while (__hip_atomic_load(ctr, __ATOMIC_ACQUIRE, __HIP_MEMORY_SCOPE_AGENT) < target)
            __builtin_amdgcn_s_sleep(2);
    }
    __syncthreads();
    __threadfence();                       // acquire: invalidate stale lines
}

__global__ __launch_bounds__(512, 4) void fused_kernel(
    const float* __restrict__ x,
    const float* __restrict__ Wk, const float* __restrict__ Wq,
    const float* __restrict__ Wv,
    bf16_t* __restrict__ qh, bf16_t* __restrict__ ql,
    bf16_t* __restrict__ kh, bf16_t* __restrict__ kl,
    bf16_t* __restrict__ vh,
    float* __restrict__ Oacc, float* __restrict__ lacc,
    float* __restrict__ out, unsigned* __restrict__ ctr)
{
    __shared__ __attribute__((aligned(16))) char smem[73728];   // 72 KB union

    const int tid  = threadIdx.x;
    const int wid  = tid >> 6;
    const int lane = tid & 63;
    const int quad = lane >> 4;
    const int l16  = lane & 15;

    // ===================== Phase 1: QKV projection =====================
    // M-tile 32, K-step 32, 512 blocks, reg-staged fused W-convert, 3-slot
    // LDS rotation (3 x 24 KB), ONE raw barrier per iteration (R12 scheme).
    {
        bf16_t* Wlds0 = (bf16_t*)smem;
        const int mhalf = wid >> 2;           // 16-row group 0..1
        const int nq    = wid & 3;            // 48-col group 0..3
        const int g     = blockIdx.x * 32 + mhalf * 16 + l16;
        const float* xrow = x + (size_t)g * C_;

        // W chunk mapping: 768 chunks of 8 fp32 per K-tile-32.
        // chunk ci -> nt=ci>>6, ln=ci&63; W row nt*16+(ln&15), col (ln>>4)*8.
        // LDS: hi group nt, lo group nt+12, elem ln*8 (lane-linear,
        // conflict-free; reader layout identical to R10/R12 which passed).
        const int nck = (tid < 256) ? 2 : 1;
        const float* ck_src[2] = {nullptr, nullptr};
        int ck_hi[2] = {0, 0}, ck_lo[2] = {0, 0};
        for (int i = 0; i < nck; ++i) {
            int ci = tid + 512 * i;
            int nt = ci >> 6, ln = ci & 63;
            int row = nt * 16 + (ln & 15);
            const float* base = (row < 64)  ? Wq + row * 1024
                              : (row < 128) ? Wk + (row - 64) * 1024
                                            : Wv + (row - 128) * 1024;
            ck_src[i] = base + (ln >> 4) * 8;
            ck_hi[i]  = nt * 512 + ln * 8;
            ck_lo[i]  = (nt + 12) * 512 + ln * 8;
        }

        f32x4 wr[4];
        auto loadW = [&](int it) {
            for (int i = 0; i < nck; ++i) {
                wr[i * 2]     = *(const f32x4*)(ck_src[i] + it * 32);
                wr[i * 2 + 1] = *(const f32x4*)(ck_src[i] + it * 32 + 4);
            }
        };
        auto convertWrite = [&](int slot) {
            bf16_t* L = Wlds0 + slot * (24 * 512);
            for (int i = 0; i < nck; ++i) {
                float wf[8];
                *(f32x4*)(wf)     = wr[i * 2];
                *(f32x4*)(wf + 4) = wr[i * 2 + 1];
                bf16x8 hv, lv;
                #pragma unroll
                for (int j = 0; j < 8; ++j) {
                    bf16_t h = (bf16_t)wf[j];
                    hv[j] = h;
                    lv[j] = (bf16_t)(wf[j] - (float)h);
                }
                *(bf16x8*)(L + ck_hi[i]) = hv;
                *(bf16x8*)(L + ck_lo[i]) = lv;
            }
        };
        auto loadx = [&](int it, f32x4* d) {
            d[0] = *(const f32x4*)(xrow + it * 32 + quad * 8);
            d[1] = *(const f32x4*)(xrow + it * 32 + quad * 8 + 4);
        };

        f32x4 x0[2], x1[2];
        loadW(0);
        loadx(0, x0);
        loadx(1, x1);
        asm volatile("s_waitcnt vmcnt(0)" ::: "memory");
        convertWrite(0);
        loadW(1);
        asm volatile("s_waitcnt lgkmcnt(0)" ::: "memory");
        SBAR();

        f32x4 acc[3];
        #pragma unroll
        for (int i = 0; i < 3; ++i) acc[i] = (f32x4){0.f, 0.f, 0.f, 0.f};

        int slot = 0;
        for (int it = 0; it < 32; ++it) {
            const int nslot = (slot == 2) ? 0 : slot + 1;
            float xv[8];
            *(f32x4*)(xv)     = x0[0];
            *(f32x4*)(xv + 4) = x0[1];
            x0[0] = x1[0]; x0[1] = x1[1];

            asm volatile("s_waitcnt vmcnt(0)" ::: "memory");
            if (it + 1 < 32) {
                convertWrite(nslot);
                if (it + 2 < 32) { loadW(it + 2); loadx(it + 2, x1); }
            }
            asm volatile("s_waitcnt lgkmcnt(0)" ::: "memory");
            SBAR();                        // ONE barrier/iter (3-slot rotation)

            bf16x8 ah, al;
            #pragma unroll
            for (int jj = 0; jj < 8; ++jj) {
                bf16_t h = (bf16_t)xv[jj];
                ah[jj] = h;
                al[jj] = (bf16_t)(xv[jj] - (float)h);
            }
            const bf16_t* L = Wlds0 + slot * (24 * 512);
            #pragma unroll
            for (int nt = 0; nt < 3; ++nt) {
                int gi = nq * 3 + nt;
                bf16x8 bh = *(const bf16x8*)(L + gi * 512 + lane * 8);
                bf16x8 bl = *(const bf16x8*)(L + (gi + 12) * 512 + lane * 8);
                acc[nt] = MFMA16(ah, bh, acc[nt]);
                acc[nt] = MFMA16(ah, bl, acc[nt]);
                acc[nt] = MFMA16(al, bh, acc[nt]);
            }
            slot = nslot;
        }

        // epilogue: D layout col=lane&15, row=quad*4+reg
        const int rowbase = blockIdx.x * 32 + mhalf * 16 + quad * 4;
        for (int nt = 0; nt < 3; ++nt) {
            int n = (nq * 3 + nt) * 16 + l16;
            for (int rr = 0; rr < 4; ++rr) {
                int grow = rowbase + rr;
                int bb = grow >> 11, t = grow & 2047;
                float v  = acc[nt][rr];
                bf16_t h = (bf16_t)v;
                if (n < 64) {
                    int off = (bb * T_ + t) * H_ + n;
                    qh[off] = h; ql[off] = (bf16_t)(v - (float)h);
                } else if (n < 128) {
                    int off = (bb * T_ + t) * H_ + (n - 64);
                    kh[off] = h; kl[off] = (bf16_t)(v - (float)h);
                } else {
                    vh[(bb * H_ + (n - 128)) * T_ + t] = h;
                }
            }
        }
        // zero Oacc+lacc: 266240 f32x4 = 512 blocks x 520
        {
            f32x4* Z = (f32x4*)Oacc + (size_t)blockIdx.x * 520;
            for (int i = tid; i < 520; i += 512)
                Z[i] = (f32x4){0.f, 0.f, 0.f, 0.f};
        }
    }

    grid_barrier(ctr, 512);

    // ===================== Phase 2: attention (R12 verbatim) ===============
    {
        bf16_t* KVbase = (bf16_t*)smem;              // [2][3][4096] = 48 KB
        bf16_t* Pbase  = (bf16_t*)(smem + 49152);    // [8][16*72]   = 18 KB
        auto kvp = [&](int bufi, int m) -> bf16_t* {
            return KVbase + (bufi * 3 + m) * 4096;
        };

        const int b  = blockIdx.x & 7;         // XCD-aligned batch
        const int gp = (blockIdx.x >> 3) & 7;  // pair index
        const int s  = blockIdx.x >> 6;        // j-slice 0..7
        const int gA = gp, gB = 15 - gp;
        const int nA = 2 * gA + 2;             // j-steps of tile A

        const int t_nt   = wid >> 1;
        const int t_kk   = wid & 1;
        const int t_l16  = tid & 15;
        const int t_quad = (tid >> 4) & 3;
        const int koff   = (t_nt * 16 + t_l16) * H_ + t_kk * 32 + t_quad * 8;
        const int voff   = (t_nt * 16 + t_l16) * T_ + t_kk * 32 + t_quad * 8;

        auto stage = [&](int j, int bufi) {
            const size_t kbase = (size_t)(b * T_ + 64 * j) * H_;
            GLL16(kh + kbase + koff, kvp(bufi, 0) + wid * 512);
            GLL16(kl + kbase + koff, kvp(bufi, 1) + wid * 512);
            GLL16(vh + (size_t)b * H_ * T_ + 64 * j + voff, kvp(bufi, 2) + wid * 512);
        };

        f32x4  O[4];
        float  rowsum[4];
        bf16x8 aqh[2], aql[2];
        int    gcur = -1;

        auto flushO = [&]() {
            #pragma unroll
            for (int rr = 0; rr < 4; ++rr) {
                int trow = b * T_ + 128 * gcur + 16 * wid + quad * 4 + rr;
                #pragma unroll
                for (int ht = 0; ht < 4; ++ht)
                    atomicAdd(Oacc + (size_t)trow * H_ + ht * 16 + l16, O[ht][rr]);
                float s_ = rowsum[rr];
                s_ += __shfl_xor(s_, 1, 64);
                s_ += __shfl_xor(s_, 2, 64);
                s_ += __shfl_xor(s_, 4, 64);
                s_ += __shfl_xor(s_, 8, 64);
                if (l16 == 0) atomicAdd(lacc + trow, s_);
            }
        };

        {
            int u0 = s;
            int j0 = (u0 < nA) ? u0 : (u0 - nA);
            stage(j0, 0);
        }

        int buf = 0;
        for (int u = s; u < 34; u += 8) {
            const int g = (u < nA) ? gA : gB;
            const int j = (u < nA) ? u : (u - nA);

            const int un = u + 8;
            if (un < 34) {
                int jn = (un < nA) ? un : (un - nA);
                stage(jn, buf ^ 1);
                asm volatile("s_waitcnt vmcnt(3)" ::: "memory");
            } else {
                asm volatile("s_waitcnt vmcnt(0)" ::: "memory");
            }
            SBAR();                        // raw: next K/V stays in flight

            if (g != gcur) {
                if (gcur >= 0) flushO();
                gcur = g;
                const size_t qoff = (size_t)(b * T_ + 128 * g + 16 * wid + l16) * H_;
                #pragma unroll
                for (int kk = 0; kk < 2; ++kk) {
                    aqh[kk] = *(const bf16x8*)(qh + qoff + kk * 32 + quad * 8);
                    aql[kk] = *(const bf16x8*)(ql + qoff + kk * 32 + quad * 8);
                }
                #pragma unroll
                for (int i = 0; i < 4; ++i) { O[i] = (f32x4){0.f,0.f,0.f,0.f}; rowsum[i] = 0.f; }
            }

            const bf16_t* Kh = kvp(buf, 0);
            const bf16_t* Kl = kvp(buf, 1);
            f32x4 S[4];
            #pragma unroll
            for (int i = 0; i < 4; ++i) S[i] = (f32x4){0.f,0.f,0.f,0.f};
            #pragma unroll
            for (int nt = 0; nt < 4; ++nt) {
                #pragma unroll
                for (int kk = 0; kk < 2; ++kk) {
                    bf16x8 bh = *(const bf16x8*)(Kh + (nt * 2 + kk) * 512 + lane * 8);
                    bf16x8 bl = *(const bf16x8*)(Kl + (nt * 2 + kk) * 512 + lane * 8);
                    S[nt] = MFMA16(aqh[kk], bh, S[nt]);
                    S[nt] = MFMA16(aqh[kk], bl, S[nt]);
                    S[nt] = MFMA16(aql[kk], bh, S[nt]);
                }
            }

            bf16_t* Pw = Pbase + wid * (16 * 72);
            const int rloc = 128 * g + 16 * wid + quad * 4;
            #pragma unroll
            for (int nt = 0; nt < 4; ++nt) {
                int colt = 64 * j + nt * 16 + l16;
                #pragma unroll
                for (int rr = 0; rr < 4; ++rr) {
                    float pv = (colt <= rloc + rr)
                             ? __expf(fmaf(S[nt][rr], 0.125f, -20.0f)) : 0.f;
                    rowsum[rr] += pv;
                    Pw[(quad * 4 + rr) * 72 + nt * 16 + l16] = (bf16_t)pv;
                }
            }

            bf16x8 ap0 = *(const bf16x8*)(Pw + l16 * 72 + quad * 8);
            bf16x8 ap1 = *(const bf16x8*)(Pw + l16 * 72 + 32 + quad * 8);

            const bf16_t* Vt = kvp(buf, 2);
            #pragma unroll
            for (int ht = 0; ht < 4; ++ht) {
                bf16x8 bv0 = *(const bf16x8*)(Vt + (ht * 2 + 0) * 512 + lane * 8);
                bf16x8 bv1 = *(const bf16x8*)(Vt + (ht * 2 + 1) * 512 + lane * 8);
                O[ht] = MFMA16(ap0, bv0, O[ht]);
                O[ht] = MFMA16(ap1, bv1, O[ht]);
            }

            SBAR();                        // done reading buf before re-stage
            buf ^= 1;
        }
        if (gcur >= 0) flushO();
    }

    grid_barrier(ctr, 1024);

    // ===================== Phase 3: out = Oacc / lacc ======================
    {
        int i = blockIdx.x * 512 + tid;            // 512*512 = 262144 exact
        f32x4 o   = ((const f32x4*)Oacc)[i];
        float inv = 1.0f / lacc[i >> 4];
        ((f32x4*)out)[i] = o * inv;
    }
}

// ---------------------------------------------------------------------------
extern "C" void kernel_launch(void* const* d_in, const int* in_sizes, int n_in,
                              void* d_out, int out_size, void* d_ws, size_t ws_size,
                              hipStream_t stream)
{
    const float* x  = (const float*)d_in[0];
    const float* Wk = (const float*)d_in[1];
    const float* Wq = (const float*)d_in[2];
    const float* Wv = (const float*)d_in[3];
    float* out = (float*)d_out;

    char* ws = (char*)d_ws;
    const size_t QSZ = (size_t)B_ * T_ * H_ * sizeof(bf16_t);  // 2097152
    bf16_t* qh   = (bf16_t*)(ws);
    bf16_t* ql   = (bf16_t*)(ws + 1 * QSZ);
    bf16_t* kh   = (bf16_t*)(ws + 2 * QSZ);
    bf16_t* kl   = (bf16_t*)(ws + 3 * QSZ);
    bf16_t* vh   = (bf16_t*)(ws + 4 * QSZ);
    float*  Oacc = (float*)(ws + 5 * QSZ);                     // 4 MB
    float*  lacc = (float*)(ws + 5 * QSZ + (size_t)B_ * T_ * H_ * 4);
    unsigned* ctr = (unsigned*)(ws + 5 * QSZ
                                + (size_t)B_ * T_ * H_ * 4 + (size_t)B_ * T_ * 4);

    // zero the grid-barrier counter (4 bytes) every launch; graph-capturable
    hipMemsetAsync(ctr, 0, sizeof(unsigned), stream);
    hipLaunchKernelGGL(fused_kernel, dim3(512), dim3(512), 0, stream,
                       x, Wk, Wq, Wv, qh, ql, kh, kl, vh, Oacc, lacc, out, ctr);
}